// Round 1
// baseline (1454.054 us; speedup 1.0000x reference)
//
#include <hip/hip_runtime.h>
#include <hip/hip_bf16.h>

#define B 32768
#define D 1024
#define SEL 512
#define E 6
#define K 3
#define SH 32
#define HID 128
#define XT 544  // SEL + SH

// ---------------- K0: per-expert top-512 column selection ----------------
// sel_idx[e][rank] = column index; rank by (value desc, index asc) == lax.top_k
__global__ void k_sel(const float* __restrict__ ml, int* __restrict__ sel) {
    __shared__ float row[D];
    const int e = blockIdx.x, t = threadIdx.x;
    row[t] = ml[e * D + t];
    __syncthreads();
    const float v = row[t];
    int rank = 0;
    for (int i = 0; i < D; ++i) {
        float u = row[i];
        rank += (u > v) || (u == v && i < t);
    }
    if (rank < SEL) sel[e * SEL + rank] = t;
}

// ---------------- K1: Wfull = Wv @ Wo @ Wsp  (512x32), bfull = bo@Wsp + bsp ----
__global__ void k_wfull(const float* __restrict__ Wv, const float* __restrict__ Wo,
                        const float* __restrict__ bo, const float* __restrict__ Wsp,
                        const float* __restrict__ bsp,
                        float* __restrict__ Wfull, float* __restrict__ bfull) {
    __shared__ float ws[64 * SH];  // WoWsp
    const int t = threadIdx.x;  // 256
    for (int idx = t; idx < 64 * SH; idx += 256) {
        int i = idx >> 5, j = idx & (SH - 1);
        float p = 0.f;
        for (int c = 0; c < 512; ++c) p += Wo[i * 512 + c] * Wsp[c * SH + j];
        ws[idx] = p;
    }
    __syncthreads();
    for (int idx = t; idx < 512 * SH; idx += 256) {
        int c = idx >> 5, j = idx & (SH - 1);
        float p = 0.f;
        for (int i = 0; i < 64; ++i) p += Wv[c * 64 + i] * ws[i * SH + j];
        Wfull[idx] = p;
    }
    if (t < SH) {
        float p = bsp[t];
        for (int c = 0; c < 512; ++c) p += bo[c] * Wsp[c * SH + t];
        bfull[t] = p;
    }
}

// ---------------- K2: fused per-token forward ----------------
__global__ __launch_bounds__(256) void k_main(
    const float* __restrict__ x, const float* __restrict__ Wg, const float* __restrict__ bg,
    const int* __restrict__ sel, const float* __restrict__ Wfull, const float* __restrict__ bfull,
    const float* __restrict__ W1, const float* __restrict__ b1,
    const float* __restrict__ W2, const float* __restrict__ b2,
    float* __restrict__ out) {
    __shared__ float xs[D];
    __shared__ float xsel[XT];
    __shared__ float sinfo[SH];
    __shared__ float red[256];
    __shared__ float gl[E];
    __shared__ int   tidx[K];
    __shared__ float tw[K];

    const int b = blockIdx.x, t = threadIdx.x;

    // stage x row (coalesced float4: 256 thr x 16B = 4KB)
    ((float4*)xs)[t] = ((const float4*)(x + (size_t)b * D))[t];
    __syncthreads();

    // gate partials: 6 experts x 32 threads; shared_info: 32 threads serial 512-dot
    if (t < E * 32) {
        const int e = t >> 5, l = t & 31;
        float p = 0.f;
        for (int c = l; c < D; c += 32) p += xs[c] * Wg[c * E + e];
        red[t] = p;
    } else if (t < E * 32 + SH) {
        const int j = t - E * 32;
        float p = bfull[j];
        for (int c = 0; c < 512; ++c) p += xs[512 + c] * Wfull[c * SH + j];
        sinfo[j] = p;
    }
    __syncthreads();
    if (t < E) {
        float s = bg[t];
        for (int l = 0; l < 32; ++l) s += red[t * 32 + l];
        gl[t] = s;
    }
    __syncthreads();
    if (t == 0) {
        // top-3 (desc value, ties -> lower index) + softmax
        bool used[E] = {false, false, false, false, false, false};
        float sc[K];
        for (int k = 0; k < K; ++k) {
            float best = -1e30f; int bi = 0;
            for (int e = 0; e < E; ++e)
                if (!used[e] && gl[e] > best) { best = gl[e]; bi = e; }
            used[bi] = true; sc[k] = best; tidx[k] = bi;
        }
        float m = sc[0], sum = 0.f, w[K];
        for (int k = 0; k < K; ++k) { w[k] = __expf(sc[k] - m); sum += w[k]; }
        for (int k = 0; k < K; ++k) tw[k] = w[k] / sum;
    }
    __syncthreads();

    float out_acc = 0.f;
    for (int k = 0; k < K; ++k) {
        const int e = tidx[k];
        // gather selected columns + shared_info into xsel[544]
        const int* se = sel + e * SEL;
        xsel[t]       = xs[se[t]];
        xsel[t + 256] = xs[se[t + 256]];
        if (t < SH) xsel[SEL + t] = sinfo[t];
        __syncthreads();
        if (t < HID) {
            const float* w1 = W1 + (size_t)e * XT * HID + t;
            float acc = b1[e * HID + t];
            #pragma unroll 4
            for (int s = 0; s < XT; ++s) acc += xsel[s] * w1[(size_t)s * HID];
            float h = fmaxf(acc, 0.f);
            red[t] = h * W2[e * HID + t];
        }
        __syncthreads();
        for (int off = 64; off >= 1; off >>= 1) {
            if (t < off) red[t] += red[t + off];
            __syncthreads();
        }
        if (t == 0) out_acc += tw[k] * (red[0] + b2[e]);
        __syncthreads();
    }
    if (t == 0) out[b] = out_acc;
}

extern "C" void kernel_launch(void* const* d_in, const int* in_sizes, int n_in,
                              void* d_out, int out_size, void* d_ws, size_t ws_size,
                              hipStream_t stream) {
    const float* x    = (const float*)d_in[0];
    // d_in[1]=Wq, d_in[2]=Wk unused
    const float* Wv   = (const float*)d_in[3];
    const float* Wo   = (const float*)d_in[4];
    const float* bo   = (const float*)d_in[5];
    const float* Wsp  = (const float*)d_in[6];
    const float* bsp  = (const float*)d_in[7];
    const float* Wg   = (const float*)d_in[8];
    const float* bg   = (const float*)d_in[9];
    const float* ml   = (const float*)d_in[10];
    const float* W1   = (const float*)d_in[11];
    const float* b1   = (const float*)d_in[12];
    const float* W2   = (const float*)d_in[13];
    const float* b2   = (const float*)d_in[14];
    float* out = (float*)d_out;

    char* ws = (char*)d_ws;
    int*   sel   = (int*)ws;                          // 6*512*4   = 12KB
    float* Wfull = (float*)(ws + 16 * 1024);          // 512*32*4  = 64KB
    float* bfull = (float*)(ws + 16 * 1024 + 64 * 1024); // 32*4

    k_sel<<<E, D, 0, stream>>>(ml, sel);
    k_wfull<<<1, 256, 0, stream>>>(Wv, Wo, bo, Wsp, bsp, Wfull, bfull);
    k_main<<<B, 256, 0, stream>>>(x, Wg, bg, sel, Wfull, bfull, W1, b1, W2, b2, out);
}

// Round 2
// 688.220 us; speedup vs baseline: 2.1128x; 2.1128x over previous
//
#include <hip/hip_runtime.h>

#define B 32768
#define D 1024
#define SEL 512
#define E 6
#define K 3
#define SH 32
#define HID 128
#define KP 1088   // padded K: 1024 (x) + 32 (sinfo) + 32 zeros = 17*64
#define NKT 17    // K tiles of 64

typedef __attribute__((ext_vector_type(8))) short bf16x8;
typedef __attribute__((ext_vector_type(4))) float f32x4;

__device__ __forceinline__ unsigned short f2bf(float f) {
  unsigned u = __float_as_uint(f);
  return (unsigned short)((u + 0x7fffu + ((u >> 16) & 1u)) >> 16);
}

__device__ __forceinline__ void gload_lds16(const void* g, void* l) {
  __builtin_amdgcn_global_load_lds(
      (const __attribute__((address_space(1))) void*)g,
      (__attribute__((address_space(3))) void*)l, 16, 0, 0);
}

// ---------------- K0: per-expert inverse selection map ----------------
// inv[e][d] = rank of column d in top-512 of mask_logits[e] (desc, idx asc), else -1
__global__ void k_sel(const float* __restrict__ ml, int* __restrict__ inv) {
  __shared__ float row[D];
  const int e = blockIdx.x, t = threadIdx.x;
  row[t] = ml[e * D + t];
  __syncthreads();
  const float v = row[t];
  int rank = 0;
  for (int i = 0; i < D; ++i) {
    float u = row[i];
    rank += (u > v) || (u == v && i < t);
  }
  inv[e * D + t] = (rank < SEL) ? rank : -1;
}

// ---------------- K1: Wfull = Wv@Wo@Wsp (512x32), bfull = bo@Wsp + bsp ----
__global__ void k_wfull(const float* __restrict__ Wv, const float* __restrict__ Wo,
                        const float* __restrict__ bo, const float* __restrict__ Wsp,
                        const float* __restrict__ bsp,
                        float* __restrict__ Wfull, float* __restrict__ bfull) {
  __shared__ float wsh[64 * SH];
  const int t = threadIdx.x;
  for (int idx = t; idx < 64 * SH; idx += 256) {
    int i = idx >> 5, j = idx & (SH - 1);
    float p = 0.f;
    for (int c = 0; c < 512; ++c) p += Wo[i * 512 + c] * Wsp[c * SH + j];
    wsh[idx] = p;
  }
  __syncthreads();
  for (int idx = t; idx < 512 * SH; idx += 256) {
    int c = idx >> 5, j = idx & (SH - 1);
    float p = 0.f;
    for (int i = 0; i < 64; ++i) p += Wv[c * 64 + i] * wsh[i * SH + j];
    Wfull[idx] = p;
  }
  if (t < SH) {
    float p = bsp[t];
    for (int c = 0; c < 512; ++c) p += bo[c] * Wsp[c * SH + t];
    bfull[t] = p;
  }
}

// ---------------- K2: W1expT[e][h][d] (bf16, zero-scattered, transposed) ----
__global__ void k_w1t(const float* __restrict__ W1, const int* __restrict__ inv,
                      unsigned short* __restrict__ W1eT) {
  const int e = blockIdx.x >> 7, h = blockIdx.x & 127;
  unsigned short* dst = W1eT + ((size_t)e * HID + h) * KP;
  const int* iv = inv + e * D;
  const float* We = W1 + (size_t)e * (SEL + SH) * HID;
  for (int d = threadIdx.x; d < KP; d += 256) {
    float v = 0.f;
    if (d < D) {
      int s = iv[d];
      if (s >= 0) v = We[(size_t)s * HID + h];
    } else if (d < D + SH) {
      v = We[(size_t)(SEL + (d - D)) * HID + h];
    }
    dst[d] = f2bf(v);
  }
}

// ---------------- K3: gate logits + shared_info (one x pass) ----------------
__global__ __launch_bounds__(256) void k_xprep(
    const float* __restrict__ x, const float* __restrict__ Wg, const float* __restrict__ bg,
    const float* __restrict__ Wfull, const float* __restrict__ bfull,
    float* __restrict__ gl, float* __restrict__ sinfo) {
  __shared__ float xs[4][D];
  const int w = threadIdx.x >> 6, lane = threadIdx.x & 63;
  const int tok = blockIdx.x * 4 + w;
  const float4* src = (const float4*)(x + (size_t)tok * D);
  #pragma unroll
  for (int c = 0; c < 4; ++c)
    ((float4*)xs[w])[c * 64 + lane] = src[c * 64 + lane];
  // gate logits
  float gp[E] = {};
  for (int c = lane; c < D; c += 64) {
    float xv = xs[w][c];
    #pragma unroll
    for (int e2 = 0; e2 < E; ++e2) gp[e2] += xv * Wg[c * E + e2];
  }
  #pragma unroll
  for (int e2 = 0; e2 < E; ++e2) {
    float s = gp[e2];
    s += __shfl_xor(s, 1); s += __shfl_xor(s, 2); s += __shfl_xor(s, 4);
    s += __shfl_xor(s, 8); s += __shfl_xor(s, 16); s += __shfl_xor(s, 32);
    if (lane == 0) gl[(size_t)tok * E + e2] = s + bg[e2];
  }
  // shared_info: lanes = (j, half)
  const int jj = lane & 31, half = lane >> 5;
  float sp = 0.f;
  const int c0 = half * 256;
  for (int c = c0; c < c0 + 256; ++c) sp += xs[w][512 + c] * Wfull[c * SH + jj];
  sp += __shfl_xor(sp, 32);
  if (half == 0) sinfo[(size_t)tok * SH + jj] = sp + bfull[jj];
}

// ---------------- K4: per-expert dense GEMM + fused relu·W2 epilogue ----------
__global__ __launch_bounds__(256) void k_gemm(
    const float* __restrict__ x, const float* __restrict__ sinfo,
    const unsigned short* __restrict__ W1eT,
    const float* __restrict__ b1, const float* __restrict__ W2,
    const float* __restrict__ b2, float* __restrict__ eo) {
  __shared__ __align__(16) char ldsA[64 * 128];    // [row][128B] swizzled
  __shared__ __align__(16) char ldsB[128 * 128];   // [col][128B] swizzled
  __shared__ float red[2][64];

  const int t = threadIdx.x;
  const int e = blockIdx.x >> 9;       // grid = E * 512
  const int bm = blockIdx.x & 511;
  const int w = t >> 6, lane = t & 63;
  const int wm = w >> 1, wn = w & 1;
  const int g = lane >> 4, j = lane & 15;
  const int c16 = t & 15, rb = t >> 4;
  const char* Wb = (const char*)(W1eT + (size_t)e * HID * KP);

  f32x4 acc[2][4] = {};

  for (int kt = 0; kt < NKT; ++kt) {
    if (kt) __syncthreads();
    // --- stage B: global_load_lds, linear LDS dest + pre-swizzled source
    #pragma unroll
    for (int q = 0; q < 4; ++q) {
      int off = (w * 4 + q) * 1024 + lane * 16;
      int c = off >> 7, kb = off & 127;
      gload_lds16(Wb + (size_t)c * (KP * 2) + kt * 128 + (kb ^ ((c & 7) << 4)),
                  ldsB + (w * 4 + q) * 1024);
    }
    // --- stage A: fp32 -> bf16 reg-staged, swizzled ds_write
    #pragma unroll
    for (int r4 = 0; r4 < 4; ++r4) {
      int r = rb + r4 * 16;
      float4 v;
      if (kt < 16) {
        v = *(const float4*)(x + (size_t)(bm * 64 + r) * D + kt * 64 + c16 * 4);
      } else if (c16 < 8) {
        v = *(const float4*)(sinfo + (size_t)(bm * 64 + r) * SH + c16 * 4);
      } else {
        v = make_float4(0.f, 0.f, 0.f, 0.f);
      }
      ushort4 h;
      h.x = f2bf(v.x); h.y = f2bf(v.y); h.z = f2bf(v.z); h.w = f2bf(v.w);
      *(ushort4*)(ldsA + r * 128 + ((c16 * 8) ^ ((r & 7) << 4))) = h;
    }
    __syncthreads();
    // --- MFMA: 2 k-steps x (2x4 fragments)
    #pragma unroll
    for (int kk = 0; kk < 2; ++kk) {
      const int kb = kk * 64 + g * 16;
      bf16x8 aF[2], bF[4];
      #pragma unroll
      for (int fm = 0; fm < 2; ++fm) {
        int row = wm * 32 + fm * 16 + j;
        aF[fm] = *(const bf16x8*)(ldsA + row * 128 + (kb ^ ((row & 7) << 4)));
      }
      #pragma unroll
      for (int fn = 0; fn < 4; ++fn) {
        int col = wn * 64 + fn * 16 + j;
        bF[fn] = *(const bf16x8*)(ldsB + col * 128 + (kb ^ ((col & 7) << 4)));
      }
      #pragma unroll
      for (int fm = 0; fm < 2; ++fm)
        #pragma unroll
        for (int fn = 0; fn < 4; ++fn)
          acc[fm][fn] = __builtin_amdgcn_mfma_f32_16x16x32_bf16(aF[fm], bF[fn], acc[fm][fn], 0, 0, 0);
    }
  }
  // --- epilogue: h = relu(acc + b1); eo = h . W2 + b2
  float b1v[4], w2v[4];
  #pragma unroll
  for (int fn = 0; fn < 4; ++fn) {
    int col = wn * 64 + fn * 16 + j;
    b1v[fn] = b1[e * HID + col];
    w2v[fn] = W2[e * HID + col];
  }
  #pragma unroll
  for (int fm = 0; fm < 2; ++fm) {
    #pragma unroll
    for (int r = 0; r < 4; ++r) {
      float s = 0.f;
      #pragma unroll
      for (int fn = 0; fn < 4; ++fn)
        s += fmaxf(acc[fm][fn][r] + b1v[fn], 0.f) * w2v[fn];
      s += __shfl_xor(s, 1); s += __shfl_xor(s, 2);
      s += __shfl_xor(s, 4); s += __shfl_xor(s, 8);
      if (j == 0) red[wn][wm * 32 + fm * 16 + g * 4 + r] = s;
    }
  }
  __syncthreads();
  if (t < 64)
    eo[(size_t)(bm * 64 + t) * E + e] = red[0][t] + red[1][t] + b2[e];
}

// ---------------- K5: top-3 softmax combine ----------------
__global__ void k_comb(const float* __restrict__ gl, const float* __restrict__ eo,
                       float* __restrict__ out) {
  const int tok = blockIdx.x * 256 + threadIdx.x;
  float gv[E];
  #pragma unroll
  for (int e2 = 0; e2 < E; ++e2) gv[e2] = gl[(size_t)tok * E + e2];
  int idx[K]; float sc[K];
  bool used[E] = {};
  #pragma unroll
  for (int k = 0; k < K; ++k) {
    float best = -1e30f; int bi = 0;
    for (int e2 = 0; e2 < E; ++e2)
      if (!used[e2] && gv[e2] > best) { best = gv[e2]; bi = e2; }
    used[bi] = true; sc[k] = best; idx[k] = bi;
  }
  float s0 = __expf(sc[0] - sc[0]), s1 = __expf(sc[1] - sc[0]), s2 = __expf(sc[2] - sc[0]);
  float inv_s = 1.f / (s0 + s1 + s2);
  float r = s0 * eo[(size_t)tok * E + idx[0]]
          + s1 * eo[(size_t)tok * E + idx[1]]
          + s2 * eo[(size_t)tok * E + idx[2]];
  out[tok] = r * inv_s;
}

extern "C" void kernel_launch(void* const* d_in, const int* in_sizes, int n_in,
                              void* d_out, int out_size, void* d_ws, size_t ws_size,
                              hipStream_t stream) {
  const float* x   = (const float*)d_in[0];
  const float* Wv  = (const float*)d_in[3];
  const float* Wo  = (const float*)d_in[4];
  const float* bo  = (const float*)d_in[5];
  const float* Wsp = (const float*)d_in[6];
  const float* bsp = (const float*)d_in[7];
  const float* Wg  = (const float*)d_in[8];
  const float* bg  = (const float*)d_in[9];
  const float* ml  = (const float*)d_in[10];
  const float* W1  = (const float*)d_in[11];
  const float* b1  = (const float*)d_in[12];
  const float* W2  = (const float*)d_in[13];
  const float* b2  = (const float*)d_in[14];
  float* out = (float*)d_out;

  char* ws = (char*)d_ws;
  int*   inv   = (int*)ws;                                        // 24 KB
  float* Wfull = (float*)(ws + 32768);                            // 64 KB
  float* bfull = (float*)(ws + 32768 + 65536);                    // 128 B
  float* gl    = (float*)(ws + 131072);                           // 768 KB
  float* sinfo = (float*)(ws + 131072 + 786432);                  // 4 MB
  float* eo    = (float*)(ws + 131072 + 786432 + 4194304);        // 768 KB
  unsigned short* W1eT =
      (unsigned short*)(ws + 131072 + 786432 + 4194304 + 786432); // 1.63 MB

  k_sel<<<E, D, 0, stream>>>(ml, inv);
  k_wfull<<<1, 256, 0, stream>>>(Wv, Wo, bo, Wsp, bsp, Wfull, bfull);
  k_w1t<<<E * HID, 256, 0, stream>>>(W1, inv, W1eT);
  k_xprep<<<B / 4, 256, 0, stream>>>(x, Wg, bg, Wfull, bfull, gl, sinfo);
  k_gemm<<<E * (B / 64), 256, 0, stream>>>(x, sinfo, W1eT, b1, W2, b2, eo);
  k_comb<<<B / 256, 256, 0, stream>>>(gl, eo, out);
}

// Round 3
// 451.403 us; speedup vs baseline: 3.2212x; 1.5246x over previous
//
#include <hip/hip_runtime.h>

#define B 32768
#define D 1024
#define SEL 512
#define E 6
#define K 3
#define SH 32
#define HID 128
#define KP 1088   // padded K: 1024 (x) + 32 (sinfo) + 32 zeros = 17*64
#define NKT 17    // K tiles of 64

typedef __attribute__((ext_vector_type(8))) short bf16x8;
typedef __attribute__((ext_vector_type(4))) float f32x4;

__device__ __forceinline__ unsigned short f2bf(float f) {
  unsigned u = __float_as_uint(f);
  return (unsigned short)((u + 0x7fffu + ((u >> 16) & 1u)) >> 16);
}

__device__ __forceinline__ void gload_lds16(const void* g, void* l) {
  __builtin_amdgcn_global_load_lds(
      (const __attribute__((address_space(1))) void*)g,
      (__attribute__((address_space(3))) void*)l, 16, 0, 0);
}

// ---------------- K0: per-expert inverse selection map ----------------
__global__ void k_sel(const float* __restrict__ ml, int* __restrict__ inv) {
  __shared__ float row[D];
  const int e = blockIdx.x, t = threadIdx.x;
  row[t] = ml[e * D + t];
  __syncthreads();
  const float v = row[t];
  int rank = 0;
  for (int i = 0; i < D; ++i) {
    float u = row[i];
    rank += (u > v) || (u == v && i < t);
  }
  inv[e * D + t] = (rank < SEL) ? rank : -1;
}

// ---------------- K1a: WoWsp = Wo@Wsp (64x32) + bfull, parallel ----------------
// grid 65: blocks 0..63 -> row i of WoWsp; block 64 -> bfull
__global__ __launch_bounds__(256) void k_wowsp(
    const float* __restrict__ Wo, const float* __restrict__ Wsp,
    const float* __restrict__ bo, const float* __restrict__ bsp,
    float* __restrict__ WoWsp, float* __restrict__ bfull) {
  __shared__ float red[256];
  const int t = threadIdx.x;
  const int j = t & 31, chunk = t >> 5;  // 8 chunks of 64 c
  const int blk = blockIdx.x;
  float p = 0.f;
  if (blk < 64) {
    const int i = blk;
    for (int c = chunk * 64; c < chunk * 64 + 64; ++c)
      p += Wo[i * 512 + c] * Wsp[c * SH + j];
    red[t] = p;
    __syncthreads();
    if (t < 32) {
      float s = 0.f;
      #pragma unroll
      for (int k = 0; k < 8; ++k) s += red[k * 32 + j];
      WoWsp[i * SH + j] = s;
    }
  } else {
    for (int c = chunk * 64; c < chunk * 64 + 64; ++c)
      p += bo[c] * Wsp[c * SH + j];
    red[t] = p;
    __syncthreads();
    if (t < 32) {
      float s = bsp[j];
      #pragma unroll
      for (int k = 0; k < 8; ++k) s += red[k * 32 + j];
      bfull[j] = s;
    }
  }
}

// ---------------- K1b: Wfull = Wv @ WoWsp (512x32), parallel ----------------
// grid 64: each block 8 rows; thread = (row within block, j)
__global__ __launch_bounds__(256) void k_wfull2(
    const float* __restrict__ Wv, const float* __restrict__ WoWsp,
    float* __restrict__ Wfull) {
  __shared__ float wsh[64 * SH];
  const int t = threadIdx.x;
  for (int idx = t; idx < 64 * SH; idx += 256) wsh[idx] = WoWsp[idx];
  __syncthreads();
  const int c = blockIdx.x * 8 + (t >> 5), j = t & 31;
  float p = 0.f;
  #pragma unroll 8
  for (int i = 0; i < 64; ++i) p += Wv[c * 64 + i] * wsh[i * SH + j];
  Wfull[c * SH + j] = p;
}

// ---------------- K2: W1expT[e][h][d] (bf16, zero-scattered, transposed) ----
__global__ void k_w1t(const float* __restrict__ W1, const int* __restrict__ inv,
                      unsigned short* __restrict__ W1eT) {
  const int e = blockIdx.x >> 7, h = blockIdx.x & 127;
  unsigned short* dst = W1eT + ((size_t)e * HID + h) * KP;
  const int* iv = inv + e * D;
  const float* We = W1 + (size_t)e * (SEL + SH) * HID;
  for (int d = threadIdx.x; d < KP; d += 256) {
    float v = 0.f;
    if (d < D) {
      int s = iv[d];
      if (s >= 0) v = We[(size_t)s * HID + h];
    } else if (d < D + SH) {
      v = We[(size_t)(SEL + (d - D)) * HID + h];
    }
    dst[d] = f2bf(v);
  }
}

// ---------------- K3: gate logits + shared_info (one x pass) ----------------
__global__ __launch_bounds__(256) void k_xprep(
    const float* __restrict__ x, const float* __restrict__ Wg, const float* __restrict__ bg,
    const float* __restrict__ Wfull, const float* __restrict__ bfull,
    float* __restrict__ gl, float* __restrict__ sinfo) {
  __shared__ float xs[4][D];
  const int w = threadIdx.x >> 6, lane = threadIdx.x & 63;
  const int tok = blockIdx.x * 4 + w;
  const float4* src = (const float4*)(x + (size_t)tok * D);
  #pragma unroll
  for (int c = 0; c < 4; ++c)
    ((float4*)xs[w])[c * 64 + lane] = src[c * 64 + lane];
  float gp[E] = {};
  for (int c = lane; c < D; c += 64) {
    float xv = xs[w][c];
    #pragma unroll
    for (int e2 = 0; e2 < E; ++e2) gp[e2] += xv * Wg[c * E + e2];
  }
  #pragma unroll
  for (int e2 = 0; e2 < E; ++e2) {
    float s = gp[e2];
    s += __shfl_xor(s, 1); s += __shfl_xor(s, 2); s += __shfl_xor(s, 4);
    s += __shfl_xor(s, 8); s += __shfl_xor(s, 16); s += __shfl_xor(s, 32);
    if (lane == 0) gl[(size_t)tok * E + e2] = s + bg[e2];
  }
  const int jj = lane & 31, half = lane >> 5;
  float sp = 0.f;
  const int c0 = half * 256;
  for (int c = c0; c < c0 + 256; ++c) sp += xs[w][512 + c] * Wfull[c * SH + jj];
  sp += __shfl_xor(sp, 32);
  if (half == 0) sinfo[(size_t)tok * SH + jj] = sp + bfull[jj];
}

// ---------------- K4: per-expert dense GEMM + fused relu·W2 epilogue ----------
__global__ __launch_bounds__(256) void k_gemm(
    const float* __restrict__ x, const float* __restrict__ sinfo,
    const unsigned short* __restrict__ W1eT,
    const float* __restrict__ b1, const float* __restrict__ W2,
    const float* __restrict__ b2, float* __restrict__ eo) {
  __shared__ __align__(16) char ldsA[64 * 128];    // [row][128B] swizzled
  __shared__ __align__(16) char ldsB[128 * 128];   // [col][128B] swizzled
  __shared__ float red[2][64];

  const int t = threadIdx.x;
  const int e = blockIdx.x >> 9;       // grid = E * 512
  const int bm = blockIdx.x & 511;
  const int w = t >> 6, lane = t & 63;
  const int wm = w >> 1, wn = w & 1;
  const int g = lane >> 4, j = lane & 15;
  const int c16 = t & 15, rb = t >> 4;
  const char* Wb = (const char*)(W1eT + (size_t)e * HID * KP);

  f32x4 acc[2][4] = {};

  for (int kt = 0; kt < NKT; ++kt) {
    if (kt) __syncthreads();
    #pragma unroll
    for (int q = 0; q < 4; ++q) {
      int off = (w * 4 + q) * 1024 + lane * 16;
      int c = off >> 7, kb = off & 127;
      gload_lds16(Wb + (size_t)c * (KP * 2) + kt * 128 + (kb ^ ((c & 7) << 4)),
                  ldsB + (w * 4 + q) * 1024);
    }
    #pragma unroll
    for (int r4 = 0; r4 < 4; ++r4) {
      int r = rb + r4 * 16;
      float4 v;
      if (kt < 16) {
        v = *(const float4*)(x + (size_t)(bm * 64 + r) * D + kt * 64 + c16 * 4);
      } else if (c16 < 8) {
        v = *(const float4*)(sinfo + (size_t)(bm * 64 + r) * SH + c16 * 4);
      } else {
        v = make_float4(0.f, 0.f, 0.f, 0.f);
      }
      ushort4 h;
      h.x = f2bf(v.x); h.y = f2bf(v.y); h.z = f2bf(v.z); h.w = f2bf(v.w);
      *(ushort4*)(ldsA + r * 128 + ((c16 * 8) ^ ((r & 7) << 4))) = h;
    }
    __syncthreads();
    #pragma unroll
    for (int kk = 0; kk < 2; ++kk) {
      const int kb = kk * 64 + g * 16;
      bf16x8 aF[2], bF[4];
      #pragma unroll
      for (int fm = 0; fm < 2; ++fm) {
        int row = wm * 32 + fm * 16 + j;
        aF[fm] = *(const bf16x8*)(ldsA + row * 128 + (kb ^ ((row & 7) << 4)));
      }
      #pragma unroll
      for (int fn = 0; fn < 4; ++fn) {
        int col = wn * 64 + fn * 16 + j;
        bF[fn] = *(const bf16x8*)(ldsB + col * 128 + (kb ^ ((col & 7) << 4)));
      }
      #pragma unroll
      for (int fm = 0; fm < 2; ++fm)
        #pragma unroll
        for (int fn = 0; fn < 4; ++fn)
          acc[fm][fn] = __builtin_amdgcn_mfma_f32_16x16x32_bf16(aF[fm], bF[fn], acc[fm][fn], 0, 0, 0);
    }
  }
  float b1v[4], w2v[4];
  #pragma unroll
  for (int fn = 0; fn < 4; ++fn) {
    int col = wn * 64 + fn * 16 + j;
    b1v[fn] = b1[e * HID + col];
    w2v[fn] = W2[e * HID + col];
  }
  #pragma unroll
  for (int fm = 0; fm < 2; ++fm) {
    #pragma unroll
    for (int r = 0; r < 4; ++r) {
      float s = 0.f;
      #pragma unroll
      for (int fn = 0; fn < 4; ++fn)
        s += fmaxf(acc[fm][fn][r] + b1v[fn], 0.f) * w2v[fn];
      s += __shfl_xor(s, 1); s += __shfl_xor(s, 2);
      s += __shfl_xor(s, 4); s += __shfl_xor(s, 8);
      if (j == 0) red[wn][wm * 32 + fm * 16 + g * 4 + r] = s;
    }
  }
  __syncthreads();
  if (t < 64)
    eo[(size_t)(bm * 64 + t) * E + e] = red[0][t] + red[1][t] + b2[e];
}

// ---------------- K5: top-3 softmax combine ----------------
__global__ void k_comb(const float* __restrict__ gl, const float* __restrict__ eo,
                       float* __restrict__ out) {
  const int tok = blockIdx.x * 256 + threadIdx.x;
  float gv[E];
  #pragma unroll
  for (int e2 = 0; e2 < E; ++e2) gv[e2] = gl[(size_t)tok * E + e2];
  int idx[K]; float sc[K];
  bool used[E] = {};
  #pragma unroll
  for (int k = 0; k < K; ++k) {
    float best = -1e30f; int bi = 0;
    for (int e2 = 0; e2 < E; ++e2)
      if (!used[e2] && gv[e2] > best) { best = gv[e2]; bi = e2; }
    used[bi] = true; sc[k] = best; idx[k] = bi;
  }
  float s0 = __expf(sc[0] - sc[0]), s1 = __expf(sc[1] - sc[0]), s2 = __expf(sc[2] - sc[0]);
  float inv_s = 1.f / (s0 + s1 + s2);
  float r = s0 * eo[(size_t)tok * E + idx[0]]
          + s1 * eo[(size_t)tok * E + idx[1]]
          + s2 * eo[(size_t)tok * E + idx[2]];
  out[tok] = r * inv_s;
}

extern "C" void kernel_launch(void* const* d_in, const int* in_sizes, int n_in,
                              void* d_out, int out_size, void* d_ws, size_t ws_size,
                              hipStream_t stream) {
  const float* x   = (const float*)d_in[0];
  const float* Wv  = (const float*)d_in[3];
  const float* Wo  = (const float*)d_in[4];
  const float* bo  = (const float*)d_in[5];
  const float* Wsp = (const float*)d_in[6];
  const float* bsp = (const float*)d_in[7];
  const float* Wg  = (const float*)d_in[8];
  const float* bg  = (const float*)d_in[9];
  const float* ml  = (const float*)d_in[10];
  const float* W1  = (const float*)d_in[11];
  const float* b1  = (const float*)d_in[12];
  const float* W2  = (const float*)d_in[13];
  const float* b2  = (const float*)d_in[14];
  float* out = (float*)d_out;

  char* ws = (char*)d_ws;
  int*   inv   = (int*)ws;                                        // 24 KB
  float* Wfull = (float*)(ws + 32768);                            // 64 KB
  float* bfull = (float*)(ws + 32768 + 65536);                    // 128 B
  float* WoWsp = (float*)(ws + 32768 + 65536 + 4096);             // 8 KB
  float* gl    = (float*)(ws + 131072);                           // 768 KB
  float* sinfo = (float*)(ws + 131072 + 786432);                  // 4 MB
  float* eo    = (float*)(ws + 131072 + 786432 + 4194304);        // 768 KB
  unsigned short* W1eT =
      (unsigned short*)(ws + 131072 + 786432 + 4194304 + 786432); // 1.63 MB

  k_sel<<<E, D, 0, stream>>>(ml, inv);
  k_wowsp<<<65, 256, 0, stream>>>(Wo, Wsp, bo, bsp, WoWsp, bfull);
  k_wfull2<<<64, 256, 0, stream>>>(Wv, WoWsp, Wfull);
  k_w1t<<<E * HID, 256, 0, stream>>>(W1, inv, W1eT);
  k_xprep<<<B / 4, 256, 0, stream>>>(x, Wg, bg, Wfull, bfull, gl, sinfo);
  k_gemm<<<E * (B / 64), 256, 0, stream>>>(x, sinfo, W1eT, b1, W2, b2, eo);
  k_comb<<<B / 256, 256, 0, stream>>>(gl, eo, out);
}

// Round 4
// 209.594 us; speedup vs baseline: 6.9375x; 2.1537x over previous
//
#include <hip/hip_runtime.h>

#define B 32768
#define D 1024
#define SEL 512
#define E 6
#define K 3
#define SH 32
#define HID 128
#define NKT 16    // K tiles of 64 (K = D = 1024 exactly)

typedef __attribute__((ext_vector_type(8))) short bf16x8;
typedef __attribute__((ext_vector_type(4))) float f32x4;

__device__ __forceinline__ unsigned short f2bf(float f) {
  unsigned u = __float_as_uint(f);
  return (unsigned short)((u + 0x7fffu + ((u >> 16) & 1u)) >> 16);
}

__device__ __forceinline__ void gload_lds16(const void* g, void* l) {
  __builtin_amdgcn_global_load_lds(
      (const __attribute__((address_space(1))) void*)g,
      (__attribute__((address_space(3))) void*)l, 16, 0, 0);
}

// ---------------- K0: per-expert inverse selection map ----------------
__global__ void k_sel(const float* __restrict__ ml, int* __restrict__ inv) {
  __shared__ float row[D];
  const int e = blockIdx.x, t = threadIdx.x;
  row[t] = ml[e * D + t];
  __syncthreads();
  const float v = row[t];
  int rank = 0;
  for (int i = 0; i < D; ++i) {
    float u = row[i];
    rank += (u > v) || (u == v && i < t);
  }
  inv[e * D + t] = (rank < SEL) ? rank : -1;
}

// ---------------- K1a: WoWsp = Wo@Wsp (64x32) + bfull ----------------
__global__ __launch_bounds__(256) void k_wowsp(
    const float* __restrict__ Wo, const float* __restrict__ Wsp,
    const float* __restrict__ bo, const float* __restrict__ bsp,
    float* __restrict__ WoWsp, float* __restrict__ bfull) {
  __shared__ float red[256];
  const int t = threadIdx.x;
  const int j = t & 31, chunk = t >> 5;
  const int blk = blockIdx.x;
  float p = 0.f;
  if (blk < 64) {
    const int i = blk;
    for (int c = chunk * 64; c < chunk * 64 + 64; ++c)
      p += Wo[i * 512 + c] * Wsp[c * SH + j];
    red[t] = p;
    __syncthreads();
    if (t < 32) {
      float s = 0.f;
      #pragma unroll
      for (int k = 0; k < 8; ++k) s += red[k * 32 + j];
      WoWsp[i * SH + j] = s;
    }
  } else {
    for (int c = chunk * 64; c < chunk * 64 + 64; ++c)
      p += bo[c] * Wsp[c * SH + j];
    red[t] = p;
    __syncthreads();
    if (t < 32) {
      float s = bsp[j];
      #pragma unroll
      for (int k = 0; k < 8; ++k) s += red[k * 32 + j];
      bfull[j] = s;
    }
  }
}

// ---------------- K1b: Wfull = Wv @ WoWsp (512x32) ----------------
__global__ __launch_bounds__(256) void k_wfull2(
    const float* __restrict__ Wv, const float* __restrict__ WoWsp,
    float* __restrict__ Wfull) {
  __shared__ float wsh[64 * SH];
  const int t = threadIdx.x;
  for (int idx = t; idx < 64 * SH; idx += 256) wsh[idx] = WoWsp[idx];
  __syncthreads();
  const int c = blockIdx.x * 8 + (t >> 5), j = t & 31;
  float p = 0.f;
  #pragma unroll 8
  for (int i = 0; i < 64; ++i) p += Wv[c * 64 + i] * wsh[i * SH + j];
  Wfull[c * SH + j] = p;
}

// ---------------- K2: W1comb[e][h][d] bf16 (scatter + folded sinfo path) ----
// W1comb[d][h] = scatter(W1a)[d][h] + (d>=512 ? Wfull[d-512,:]@W1b[:,h] : 0)
// b1c[h] = b1[h] + bfull @ W1b[:,h]
__global__ __launch_bounds__(256) void k_w1c(
    const float* __restrict__ W1, const float* __restrict__ b1,
    const int* __restrict__ inv, const float* __restrict__ Wfull,
    const float* __restrict__ bfull,
    unsigned short* __restrict__ W1eT, float* __restrict__ b1c) {
  __shared__ float w1b[SH];
  __shared__ float bf[SH];
  const int e = blockIdx.x >> 7, h = blockIdx.x & 127;
  const int t = threadIdx.x;
  const float* We = W1 + (size_t)e * (SEL + SH) * HID;
  if (t < SH) { w1b[t] = We[(size_t)(SEL + t) * HID + h]; bf[t] = bfull[t]; }
  __syncthreads();
  const int* iv = inv + e * D;
  unsigned short* dst = W1eT + ((size_t)e * HID + h) * D;
  #pragma unroll
  for (int it = 0; it < 4; ++it) {
    int d = t + it * 256;
    int s = iv[d];
    float v = (s >= 0) ? We[(size_t)s * HID + h] : 0.f;
    if (d >= 512) {
      const float* wf = Wfull + (size_t)(d - 512) * SH;
      float p = 0.f;
      #pragma unroll
      for (int j = 0; j < SH; ++j) p += wf[j] * w1b[j];
      v += p;
    }
    dst[d] = f2bf(v);
  }
  if (t == 0) {
    float p = b1[e * HID + h];
    for (int j = 0; j < SH; ++j) p += bf[j] * w1b[j];
    b1c[e * HID + h] = p;
  }
}

// ---------------- K3: gate logits, fp32, one wave per 4 tokens ----------------
__global__ __launch_bounds__(256) void k_gate(
    const float* __restrict__ x, const float* __restrict__ Wg,
    const float* __restrict__ bg, float* __restrict__ gl) {
  const int w = threadIdx.x >> 6, lane = threadIdx.x & 63;
  const int wid = blockIdx.x * 4 + w;  // 8192 waves, 4 tokens each
  // preload this lane's Wg rows into registers: rows i*256 + lane*4 + q
  float wg[4][4][E];
  #pragma unroll
  for (int i = 0; i < 4; ++i)
    #pragma unroll
    for (int q = 0; q < 4; ++q) {
      const float* wr = Wg + (size_t)(i * 256 + lane * 4 + q) * E;
      #pragma unroll
      for (int e2 = 0; e2 < E; ++e2) wg[i][q][e2] = wr[e2];
    }
  for (int tok = wid * 4; tok < wid * 4 + 4; ++tok) {
    const float4* xp = (const float4*)(x + (size_t)tok * D);
    float acc[E] = {};
    #pragma unroll
    for (int i = 0; i < 4; ++i) {
      float4 v = xp[i * 64 + lane];
      #pragma unroll
      for (int q = 0; q < 4; ++q) {
        float xv = (&v.x)[q];
        #pragma unroll
        for (int e2 = 0; e2 < E; ++e2) acc[e2] += xv * wg[i][q][e2];
      }
    }
    #pragma unroll
    for (int e2 = 0; e2 < E; ++e2) {
      float s = acc[e2];
      s += __shfl_xor(s, 1); s += __shfl_xor(s, 2); s += __shfl_xor(s, 4);
      s += __shfl_xor(s, 8); s += __shfl_xor(s, 16); s += __shfl_xor(s, 32);
      acc[e2] = s;
    }
    if (lane == 0) {
      #pragma unroll
      for (int e2 = 0; e2 < E; ++e2) gl[(size_t)tok * E + e2] = acc[e2] + bg[e2];
    }
  }
}

// ---------------- K4: per-expert dense GEMM + fused relu·W2 epilogue ----------
__global__ __launch_bounds__(256) void k_gemm(
    const float* __restrict__ x, const unsigned short* __restrict__ W1eT,
    const float* __restrict__ b1c, const float* __restrict__ W2,
    const float* __restrict__ b2, float* __restrict__ eo) {
  __shared__ __align__(16) char ldsA[64 * 128];    // [row][128B] swizzled
  __shared__ __align__(16) char ldsB[128 * 128];   // [col][128B] swizzled
  __shared__ float red[2][64];

  const int t = threadIdx.x;
  const int e = blockIdx.x >> 9;       // grid = E * 512
  const int bm = blockIdx.x & 511;
  const int w = t >> 6, lane = t & 63;
  const int wm = w >> 1, wn = w & 1;
  const int g = lane >> 4, j = lane & 15;
  const int c16 = t & 15, rb = t >> 4;
  const char* Wb = (const char*)(W1eT + (size_t)e * HID * D);

  f32x4 acc[2][4] = {};

  for (int kt = 0; kt < NKT; ++kt) {
    if (kt) __syncthreads();
    // stage B: global_load_lds, linear LDS dest + pre-swizzled source
    #pragma unroll
    for (int q = 0; q < 4; ++q) {
      int off = (w * 4 + q) * 1024 + lane * 16;
      int c = off >> 7, kb = off & 127;
      gload_lds16(Wb + (size_t)c * (D * 2) + kt * 128 + (kb ^ ((c & 7) << 4)),
                  ldsB + (w * 4 + q) * 1024);
    }
    // stage A: fp32 -> bf16 reg-staged, swizzled ds_write
    #pragma unroll
    for (int r4 = 0; r4 < 4; ++r4) {
      int r = rb + r4 * 16;
      float4 v = *(const float4*)(x + (size_t)(bm * 64 + r) * D + kt * 64 + c16 * 4);
      ushort4 h;
      h.x = f2bf(v.x); h.y = f2bf(v.y); h.z = f2bf(v.z); h.w = f2bf(v.w);
      *(ushort4*)(ldsA + r * 128 + ((c16 * 8) ^ ((r & 7) << 4))) = h;
    }
    __syncthreads();
    #pragma unroll
    for (int kk = 0; kk < 2; ++kk) {
      const int kb = kk * 64 + g * 16;
      bf16x8 aF[2], bF[4];
      #pragma unroll
      for (int fm = 0; fm < 2; ++fm) {
        int row = wm * 32 + fm * 16 + j;
        aF[fm] = *(const bf16x8*)(ldsA + row * 128 + (kb ^ ((row & 7) << 4)));
      }
      #pragma unroll
      for (int fn = 0; fn < 4; ++fn) {
        int col = wn * 64 + fn * 16 + j;
        bF[fn] = *(const bf16x8*)(ldsB + col * 128 + (kb ^ ((col & 7) << 4)));
      }
      #pragma unroll
      for (int fm = 0; fm < 2; ++fm)
        #pragma unroll
        for (int fn = 0; fn < 4; ++fn)
          acc[fm][fn] = __builtin_amdgcn_mfma_f32_16x16x32_bf16(aF[fm], bF[fn], acc[fm][fn], 0, 0, 0);
    }
  }
  float b1v[4], w2v[4];
  #pragma unroll
  for (int fn = 0; fn < 4; ++fn) {
    int col = wn * 64 + fn * 16 + j;
    b1v[fn] = b1c[e * HID + col];
    w2v[fn] = W2[e * HID + col];
  }
  #pragma unroll
  for (int fm = 0; fm < 2; ++fm) {
    #pragma unroll
    for (int r = 0; r < 4; ++r) {
      float s = 0.f;
      #pragma unroll
      for (int fn = 0; fn < 4; ++fn)
        s += fmaxf(acc[fm][fn][r] + b1v[fn], 0.f) * w2v[fn];
      s += __shfl_xor(s, 1); s += __shfl_xor(s, 2);
      s += __shfl_xor(s, 4); s += __shfl_xor(s, 8);
      if (j == 0) red[wn][wm * 32 + fm * 16 + g * 4 + r] = s;
    }
  }
  __syncthreads();
  if (t < 64)
    eo[(size_t)(bm * 64 + t) * E + e] = red[0][t] + red[1][t] + b2[e];
}

// ---------------- K5: top-3 softmax combine ----------------
__global__ void k_comb(const float* __restrict__ gl, const float* __restrict__ eo,
                       float* __restrict__ out) {
  const int tok = blockIdx.x * 256 + threadIdx.x;
  float gv[E];
  #pragma unroll
  for (int e2 = 0; e2 < E; ++e2) gv[e2] = gl[(size_t)tok * E + e2];
  int idx[K]; float sc[K];
  bool used[E] = {};
  #pragma unroll
  for (int k = 0; k < K; ++k) {
    float best = -1e30f; int bi = 0;
    for (int e2 = 0; e2 < E; ++e2)
      if (!used[e2] && gv[e2] > best) { best = gv[e2]; bi = e2; }
    used[bi] = true; sc[k] = best; idx[k] = bi;
  }
  float s0 = 1.f, s1 = __expf(sc[1] - sc[0]), s2 = __expf(sc[2] - sc[0]);
  float inv_s = 1.f / (s0 + s1 + s2);
  float r = s0 * eo[(size_t)tok * E + idx[0]]
          + s1 * eo[(size_t)tok * E + idx[1]]
          + s2 * eo[(size_t)tok * E + idx[2]];
  out[tok] = r * inv_s;
}

extern "C" void kernel_launch(void* const* d_in, const int* in_sizes, int n_in,
                              void* d_out, int out_size, void* d_ws, size_t ws_size,
                              hipStream_t stream) {
  const float* x   = (const float*)d_in[0];
  const float* Wv  = (const float*)d_in[3];
  const float* Wo  = (const float*)d_in[4];
  const float* bo  = (const float*)d_in[5];
  const float* Wsp = (const float*)d_in[6];
  const float* bsp = (const float*)d_in[7];
  const float* Wg  = (const float*)d_in[8];
  const float* bg  = (const float*)d_in[9];
  const float* ml  = (const float*)d_in[10];
  const float* W1  = (const float*)d_in[11];
  const float* b1  = (const float*)d_in[12];
  const float* W2  = (const float*)d_in[13];
  const float* b2  = (const float*)d_in[14];
  float* out = (float*)d_out;

  char* ws = (char*)d_ws;
  int*   inv   = (int*)ws;                       // 24 KB
  float* WoWsp = (float*)(ws + 32768);           // 8 KB
  float* Wfull = (float*)(ws + 49152);           // 64 KB
  float* bfull = (float*)(ws + 114688);          // 128 B
  float* b1c   = (float*)(ws + 118784);          // 3 KB
  float* gl    = (float*)(ws + 131072);          // 768 KB
  float* eo    = (float*)(ws + 917504);          // 768 KB
  unsigned short* W1eT = (unsigned short*)(ws + 1703936);  // 1.5 MB

  k_sel<<<E, D, 0, stream>>>(ml, inv);
  k_wowsp<<<65, 256, 0, stream>>>(Wo, Wsp, bo, bsp, WoWsp, bfull);
  k_wfull2<<<64, 256, 0, stream>>>(Wv, WoWsp, Wfull);
  k_w1c<<<E * HID, 256, 0, stream>>>(W1, b1, inv, Wfull, bfull, W1eT, b1c);
  k_gate<<<2048, 256, 0, stream>>>(x, Wg, bg, gl);
  k_gemm<<<E * (B / 64), 256, 0, stream>>>(x, W1eT, b1c, W2, b2, eo);
  k_comb<<<B / 256, 256, 0, stream>>>(gl, eo, out);
}

// Round 5
// 199.540 us; speedup vs baseline: 7.2870x; 1.0504x over previous
//
#include <hip/hip_runtime.h>

#define B 32768
#define D 1024
#define SEL 512
#define E 6
#define K 3
#define SH 32
#define HID 128
#define NKT 16    // K tiles of 64 (K = D = 1024)

typedef __attribute__((ext_vector_type(8))) short bf16x8;
typedef __attribute__((ext_vector_type(4))) float f32x4;

__device__ __forceinline__ unsigned short f2bf(float f) {
  unsigned u = __float_as_uint(f);
  return (unsigned short)((u + 0x7fffu + ((u >> 16) & 1u)) >> 16);
}

__device__ __forceinline__ void gload_lds16(const void* g, void* l) {
  __builtin_amdgcn_global_load_lds(
      (const __attribute__((address_space(1))) void*)g,
      (__attribute__((address_space(3))) void*)l, 16, 0, 0);
}

// ---------------- K0: per-expert inverse selection map ----------------
__global__ void k_sel(const float* __restrict__ ml, int* __restrict__ inv) {
  __shared__ float row[D];
  const int e = blockIdx.x, t = threadIdx.x;
  row[t] = ml[e * D + t];
  __syncthreads();
  const float v = row[t];
  int rank = 0;
  for (int i = 0; i < D; ++i) {
    float u = row[i];
    rank += (u > v) || (u == v && i < t);
  }
  inv[e * D + t] = (rank < SEL) ? rank : -1;
}

// ---------------- K1a: WoWsp = Wo@Wsp (64x32) + bfull ----------------
__global__ __launch_bounds__(256) void k_wowsp(
    const float* __restrict__ Wo, const float* __restrict__ Wsp,
    const float* __restrict__ bo, const float* __restrict__ bsp,
    float* __restrict__ WoWsp, float* __restrict__ bfull) {
  __shared__ float red[256];
  const int t = threadIdx.x;
  const int j = t & 31, chunk = t >> 5;
  const int blk = blockIdx.x;
  float p = 0.f;
  if (blk < 64) {
    const int i = blk;
    for (int c = chunk * 64; c < chunk * 64 + 64; ++c)
      p += Wo[i * 512 + c] * Wsp[c * SH + j];
    red[t] = p;
    __syncthreads();
    if (t < 32) {
      float s = 0.f;
      #pragma unroll
      for (int k = 0; k < 8; ++k) s += red[k * 32 + j];
      WoWsp[i * SH + j] = s;
    }
  } else {
    for (int c = chunk * 64; c < chunk * 64 + 64; ++c)
      p += bo[c] * Wsp[c * SH + j];
    red[t] = p;
    __syncthreads();
    if (t < 32) {
      float s = bsp[j];
      #pragma unroll
      for (int k = 0; k < 8; ++k) s += red[k * 32 + j];
      bfull[j] = s;
    }
  }
}

// ---------------- K1b: Wfull = Wv @ WoWsp (512x32) ----------------
__global__ __launch_bounds__(256) void k_wfull2(
    const float* __restrict__ Wv, const float* __restrict__ WoWsp,
    float* __restrict__ Wfull) {
  __shared__ float wsh[64 * SH];
  const int t = threadIdx.x;
  for (int idx = t; idx < 64 * SH; idx += 256) wsh[idx] = WoWsp[idx];
  __syncthreads();
  const int c = blockIdx.x * 8 + (t >> 5), j = t & 31;
  float p = 0.f;
  #pragma unroll 8
  for (int i = 0; i < 64; ++i) p += Wv[c * 64 + i] * wsh[i * SH + j];
  Wfull[c * SH + j] = p;
}

// ---------------- K2: W1comb[e][h][d] bf16 (scatter + folded sinfo) ----------
__global__ __launch_bounds__(256) void k_w1c(
    const float* __restrict__ W1, const float* __restrict__ b1,
    const int* __restrict__ inv, const float* __restrict__ Wfull,
    const float* __restrict__ bfull,
    unsigned short* __restrict__ W1eT, float* __restrict__ b1c) {
  __shared__ float w1b[SH];
  __shared__ float bf[SH];
  const int e = blockIdx.x >> 7, h = blockIdx.x & 127;
  const int t = threadIdx.x;
  const float* We = W1 + (size_t)e * (SEL + SH) * HID;
  if (t < SH) { w1b[t] = We[(size_t)(SEL + t) * HID + h]; bf[t] = bfull[t]; }
  __syncthreads();
  const int* iv = inv + e * D;
  unsigned short* dst = W1eT + ((size_t)e * HID + h) * D;
  #pragma unroll
  for (int it = 0; it < 4; ++it) {
    int d = t + it * 256;
    int s = iv[d];
    float v = (s >= 0) ? We[(size_t)s * HID + h] : 0.f;
    if (d >= 512) {
      const float* wf = Wfull + (size_t)(d - 512) * SH;
      float p = 0.f;
      #pragma unroll
      for (int j = 0; j < SH; ++j) p += wf[j] * w1b[j];
      v += p;
    }
    dst[d] = f2bf(v);
  }
  if (t == 0) {
    float p = b1[e * HID + h];
    for (int j = 0; j < SH; ++j) p += bf[j] * w1b[j];
    b1c[e * HID + h] = p;
  }
}

// ---------------- K3: gate logits (fp32) + optional bf16 x conversion -------
template<bool WRITE_XBF>
__global__ __launch_bounds__(256) void k_xbf_gate(
    const float* __restrict__ x, const float* __restrict__ Wg,
    const float* __restrict__ bg, unsigned short* __restrict__ xbf,
    float* __restrict__ gl) {
  const int w = threadIdx.x >> 6, lane = threadIdx.x & 63;
  const int wid = blockIdx.x * 4 + w;
  float wg[4][4][E];
  #pragma unroll
  for (int i = 0; i < 4; ++i)
    #pragma unroll
    for (int q = 0; q < 4; ++q) {
      const float* wr = Wg + (size_t)(i * 256 + lane * 4 + q) * E;
      #pragma unroll
      for (int e2 = 0; e2 < E; ++e2) wg[i][q][e2] = wr[e2];
    }
  for (int tok = wid * 4; tok < wid * 4 + 4; ++tok) {
    const float4* xp = (const float4*)(x + (size_t)tok * D);
    float acc[E] = {};
    #pragma unroll
    for (int i = 0; i < 4; ++i) {
      float4 v = xp[i * 64 + lane];
      if (WRITE_XBF) {
        ushort4 h4;
        h4.x = f2bf(v.x); h4.y = f2bf(v.y); h4.z = f2bf(v.z); h4.w = f2bf(v.w);
        *(ushort4*)((char*)xbf + (size_t)tok * 2048 + i * 512 + lane * 8) = h4;
      }
      #pragma unroll
      for (int q = 0; q < 4; ++q) {
        float xv = (&v.x)[q];
        #pragma unroll
        for (int e2 = 0; e2 < E; ++e2) acc[e2] += xv * wg[i][q][e2];
      }
    }
    #pragma unroll
    for (int e2 = 0; e2 < E; ++e2) {
      float s = acc[e2];
      s += __shfl_xor(s, 1); s += __shfl_xor(s, 2); s += __shfl_xor(s, 4);
      s += __shfl_xor(s, 8); s += __shfl_xor(s, 16); s += __shfl_xor(s, 32);
      acc[e2] = s;
    }
    if (lane == 0) {
      #pragma unroll
      for (int e2 = 0; e2 < E; ++e2) gl[(size_t)tok * E + e2] = acc[e2] + bg[e2];
    }
  }
}

// ---------------- K4: top-3 + softmax -> per-expert compacted lists ---------
__global__ __launch_bounds__(256) void k_topk(
    const float* __restrict__ gl, int* __restrict__ cnt,
    int* __restrict__ clist, float* __restrict__ wlist) {
  const int tok = blockIdx.x * 256 + threadIdx.x;
  const int lane = threadIdx.x & 63;
  float gv[E];
  #pragma unroll
  for (int e2 = 0; e2 < E; ++e2) gv[e2] = gl[(size_t)tok * E + e2];
  int idx[K]; float sc[K];
  bool used[E] = {};
  #pragma unroll
  for (int k = 0; k < K; ++k) {
    float best = -1e30f; int bi = 0;
    for (int e2 = 0; e2 < E; ++e2)
      if (!used[e2] && gv[e2] > best) { best = gv[e2]; bi = e2; }
    used[bi] = true; sc[k] = best; idx[k] = bi;
  }
  float s1 = __expf(sc[1] - sc[0]), s2 = __expf(sc[2] - sc[0]);
  float inv_s = 1.f / (1.f + s1 + s2);
  float tw[K] = {inv_s, s1 * inv_s, s2 * inv_s};
  const unsigned long long below = (1ULL << lane) - 1ULL;
  #pragma unroll
  for (int e2 = 0; e2 < E; ++e2) {
    int myk = -1;
    #pragma unroll
    for (int k = 0; k < K; ++k) if (idx[k] == e2) myk = k;
    unsigned long long m = __ballot(myk >= 0);
    if (m) {
      int tot = __popcll(m);
      int leader = __ffsll((long long)m) - 1;
      int base = 0;
      if (lane == leader) base = atomicAdd(&cnt[e2], tot);
      base = __shfl(base, leader);
      if (myk >= 0) {
        int pos = base + __popcll(m & below);
        clist[e2 * B + pos] = (tok << 2) | myk;
        wlist[e2 * B + pos] = tw[myk];
      }
    }
  }
}

// ---------------- K5: compacted per-expert GEMM + relu·W2 epilogue ----------
// AMODE 0: A from pre-converted bf16 xbf via global_load_lds (inverse-swz src)
// AMODE 1: A from fp32 x, reg-staged cvt (fallback when ws too small for xbf)
template<int AMODE>
__global__ __launch_bounds__(256) void k_gemm(
    const float* __restrict__ x, const unsigned short* __restrict__ xbf,
    const unsigned short* __restrict__ W1eT,
    const int* __restrict__ cnt, const int* __restrict__ clist,
    const float* __restrict__ wlist,
    const float* __restrict__ b1c, const float* __restrict__ W2,
    const float* __restrict__ b2, float* __restrict__ eo4) {
  __shared__ __align__(16) char ldsA[128 * 128];
  __shared__ __align__(16) char ldsB[128 * 128];
  __shared__ int tokl[128];
  __shared__ float red[128];

  const int t = threadIdx.x;
  const int e = blockIdx.x >> 8;     // grid = E * 256
  const int bm = blockIdx.x & 255;
  const int n = cnt[e];
  if (bm * 128 >= n) return;
  const int cb = e * B;

  if (t < 128) {
    int gr = bm * 128 + t;
    tokl[t] = clist[cb + (gr < n ? gr : 0)] >> 2;
  }
  __syncthreads();

  const int w = t >> 6, lane = t & 63;
  const int g = lane >> 4, j = lane & 15;
  const int swz = ((lane & 7) * 16) ^ ((lane >> 3) << 4);

  // per-lane staging sources (row/col & 7 == lane>>3 for all q, w)
  const char* srcB[4];
  #pragma unroll
  for (int q = 0; q < 4; ++q)
    srcB[q] = (const char*)W1eT +
              (size_t)(e * HID + w * 32 + q * 8 + (lane >> 3)) * (D * 2) + swz;
  const char* srcA[4];
  if (AMODE == 0) {
    #pragma unroll
    for (int q = 0; q < 4; ++q)
      srcA[q] = (const char*)xbf +
                (size_t)tokl[w * 32 + q * 8 + (lane >> 3)] * 2048 + swz;
  }

  f32x4 acc[2][8] = {};

  for (int kt = 0; kt < NKT; ++kt) {
    if (kt) __syncthreads();
    if (AMODE == 0) {
      #pragma unroll
      for (int q = 0; q < 4; ++q)
        gload_lds16(srcA[q] + kt * 128, ldsA + w * 4096 + q * 1024);
    }
    #pragma unroll
    for (int q = 0; q < 4; ++q)
      gload_lds16(srcB[q] + kt * 128, ldsB + w * 4096 + q * 1024);
    if (AMODE == 1) {
      #pragma unroll
      for (int it = 0; it < 8; ++it) {
        int r = (t >> 4) + it * 16;
        const float4 v =
            *(const float4*)(x + (size_t)tokl[r] * D + kt * 64 + (t & 15) * 4);
        ushort4 h4;
        h4.x = f2bf(v.x); h4.y = f2bf(v.y); h4.z = f2bf(v.z); h4.w = f2bf(v.w);
        *(ushort4*)(ldsA + r * 128 + (((t & 15) * 8) ^ ((r & 7) << 4))) = h4;
      }
    }
    __syncthreads();
    #pragma unroll
    for (int kk = 0; kk < 2; ++kk) {
      const int kb = kk * 64 + g * 16;
      bf16x8 aF[2];
      #pragma unroll
      for (int fm = 0; fm < 2; ++fm) {
        int row = w * 32 + fm * 16 + j;
        aF[fm] = *(const bf16x8*)(ldsA + row * 128 + (kb ^ ((row & 7) << 4)));
      }
      #pragma unroll
      for (int fn = 0; fn < 8; ++fn) {
        int col = fn * 16 + j;
        bf16x8 bF = *(const bf16x8*)(ldsB + col * 128 + (kb ^ ((col & 7) << 4)));
        acc[0][fn] = __builtin_amdgcn_mfma_f32_16x16x32_bf16(aF[0], bF, acc[0][fn], 0, 0, 0);
        acc[1][fn] = __builtin_amdgcn_mfma_f32_16x16x32_bf16(aF[1], bF, acc[1][fn], 0, 0, 0);
      }
    }
  }

  float vb1[8], vw2[8];
  #pragma unroll
  for (int fn = 0; fn < 8; ++fn) {
    int col = fn * 16 + j;
    vb1[fn] = b1c[e * HID + col];
    vw2[fn] = W2[e * HID + col];
  }
  #pragma unroll
  for (int fm = 0; fm < 2; ++fm) {
    #pragma unroll
    for (int r = 0; r < 4; ++r) {
      float s = 0.f;
      #pragma unroll
      for (int fn = 0; fn < 8; ++fn)
        s += fmaxf(acc[fm][fn][r] + vb1[fn], 0.f) * vw2[fn];
      s += __shfl_xor(s, 1); s += __shfl_xor(s, 2);
      s += __shfl_xor(s, 4); s += __shfl_xor(s, 8);
      if (j == 0) red[w * 32 + fm * 16 + g * 4 + r] = s;
    }
  }
  __syncthreads();
  if (t < 128) {
    int gr = bm * 128 + t;
    if (gr < n) {
      int en = clist[cb + gr];
      eo4[(size_t)(en >> 2) * 4 + (en & 3)] = wlist[cb + gr] * (red[t] + b2[e]);
    }
  }
}

// ---------------- K6: sum the 3 weighted slots ----------------
__global__ void k_comb2(const float* __restrict__ eo4, float* __restrict__ out) {
  const int tok = blockIdx.x * 256 + threadIdx.x;
  float4 v = *(const float4*)(eo4 + (size_t)tok * 4);
  out[tok] = v.x + v.y + v.z;
}

extern "C" void kernel_launch(void* const* d_in, const int* in_sizes, int n_in,
                              void* d_out, int out_size, void* d_ws, size_t ws_size,
                              hipStream_t stream) {
  const float* x   = (const float*)d_in[0];
  const float* Wv  = (const float*)d_in[3];
  const float* Wo  = (const float*)d_in[4];
  const float* bo  = (const float*)d_in[5];
  const float* Wsp = (const float*)d_in[6];
  const float* bsp = (const float*)d_in[7];
  const float* Wg  = (const float*)d_in[8];
  const float* bg  = (const float*)d_in[9];
  const float* ml  = (const float*)d_in[10];
  const float* W1  = (const float*)d_in[11];
  const float* b1  = (const float*)d_in[12];
  const float* W2  = (const float*)d_in[13];
  const float* b2  = (const float*)d_in[14];
  float* out = (float*)d_out;

  char* ws = (char*)d_ws;
  int*   inv   = (int*)ws;                       // 24 KB
  float* WoWsp = (float*)(ws + 32768);           // 8 KB
  float* Wfull = (float*)(ws + 49152);           // 64 KB
  float* bfull = (float*)(ws + 114688);          // 128 B
  float* b1c   = (float*)(ws + 118784);          // 3 KB
  int*   cnt   = (int*)(ws + 126976);            // 32 B
  float* gl    = (float*)(ws + 131072);          // 768 KB
  int*   clist = (int*)(ws + 917504);            // 768 KB
  float* wlist = (float*)(ws + 1703936);         // 768 KB
  float* eo4   = (float*)(ws + 2490368);         // 512 KB
  unsigned short* W1eT = (unsigned short*)(ws + 3014656);  // 1.5 MB
  unsigned short* xbf  = (unsigned short*)(ws + 4587520);  // 64 MB (optional)
  const bool use_xbf = ws_size >= (size_t)4587520 + (size_t)B * D * 2;

  k_sel<<<E, D, 0, stream>>>(ml, inv);
  k_wowsp<<<65, 256, 0, stream>>>(Wo, Wsp, bo, bsp, WoWsp, bfull);
  k_wfull2<<<64, 256, 0, stream>>>(Wv, WoWsp, Wfull);
  k_w1c<<<E * HID, 256, 0, stream>>>(W1, b1, inv, Wfull, bfull, W1eT, b1c);
  hipMemsetAsync(cnt, 0, 32, stream);
  if (use_xbf)
    k_xbf_gate<true><<<B / 16, 256, 0, stream>>>(x, Wg, bg, xbf, gl);
  else
    k_xbf_gate<false><<<B / 16, 256, 0, stream>>>(x, Wg, bg, xbf, gl);
  k_topk<<<B / 256, 256, 0, stream>>>(gl, cnt, clist, wlist);
  if (use_xbf)
    k_gemm<0><<<E * 256, 256, 0, stream>>>(x, xbf, W1eT, cnt, clist, wlist, b1c, W2, b2, eo4);
  else
    k_gemm<1><<<E * 256, 256, 0, stream>>>(x, xbf, W1eT, cnt, clist, wlist, b1c, W2, b2, eo4);
  k_comb2<<<B / 256, 256, 0, stream>>>(eo4, out);
}

// Round 6
// 197.934 us; speedup vs baseline: 7.3462x; 1.0081x over previous
//
#include <hip/hip_runtime.h>

#define B 32768
#define D 1024
#define SEL 512
#define E 6
#define K 3
#define SH 32
#define HID 128
#define NKT 16    // K tiles of 64 (K = D = 1024)

typedef __attribute__((ext_vector_type(8))) short bf16x8;
typedef __attribute__((ext_vector_type(4))) float f32x4;

__device__ __forceinline__ unsigned short f2bf(float f) {
  unsigned u = __float_as_uint(f);
  return (unsigned short)((u + 0x7fffu + ((u >> 16) & 1u)) >> 16);
}

__device__ __forceinline__ void gload_lds16(const void* g, void* l) {
  __builtin_amdgcn_global_load_lds(
      (const __attribute__((address_space(1))) void*)g,
      (__attribute__((address_space(3))) void*)l, 16, 0, 0);
}

// ---------------- K0: per-expert inverse selection map (+ cnt zeroing) -------
__global__ void k_sel(const float* __restrict__ ml, int* __restrict__ inv,
                      int* __restrict__ cnt) {
  __shared__ float row[D];
  const int e = blockIdx.x, t = threadIdx.x;
  if (t == 0) cnt[e] = 0;   // zero the compaction counters (replaces memset)
  row[t] = ml[e * D + t];
  __syncthreads();
  const float v = row[t];
  int rank = 0;
  for (int i = 0; i < D; ++i) {
    float u = row[i];
    rank += (u > v) || (u == v && i < t);
  }
  inv[e * D + t] = (rank < SEL) ? rank : -1;
}

// ---------------- K1a: WoWsp = Wo@Wsp (64x32) + bfull ----------------
__global__ __launch_bounds__(256) void k_wowsp(
    const float* __restrict__ Wo, const float* __restrict__ Wsp,
    const float* __restrict__ bo, const float* __restrict__ bsp,
    float* __restrict__ WoWsp, float* __restrict__ bfull) {
  __shared__ float red[256];
  const int t = threadIdx.x;
  const int j = t & 31, chunk = t >> 5;
  const int blk = blockIdx.x;
  float p = 0.f;
  if (blk < 64) {
    const int i = blk;
    for (int c = chunk * 64; c < chunk * 64 + 64; ++c)
      p += Wo[i * 512 + c] * Wsp[c * SH + j];
    red[t] = p;
    __syncthreads();
    if (t < 32) {
      float s = 0.f;
      #pragma unroll
      for (int k = 0; k < 8; ++k) s += red[k * 32 + j];
      WoWsp[i * SH + j] = s;
    }
  } else {
    for (int c = chunk * 64; c < chunk * 64 + 64; ++c)
      p += bo[c] * Wsp[c * SH + j];
    red[t] = p;
    __syncthreads();
    if (t < 32) {
      float s = bsp[j];
      #pragma unroll
      for (int k = 0; k < 8; ++k) s += red[k * 32 + j];
      bfull[j] = s;
    }
  }
}

// ---------------- K1b: Wfull = Wv @ WoWsp (512x32) ----------------
__global__ __launch_bounds__(256) void k_wfull2(
    const float* __restrict__ Wv, const float* __restrict__ WoWsp,
    float* __restrict__ Wfull) {
  __shared__ float wsh[64 * SH];
  const int t = threadIdx.x;
  for (int idx = t; idx < 64 * SH; idx += 256) wsh[idx] = WoWsp[idx];
  __syncthreads();
  const int c = blockIdx.x * 8 + (t >> 5), j = t & 31;
  float p = 0.f;
  #pragma unroll 8
  for (int i = 0; i < 64; ++i) p += Wv[c * 64 + i] * wsh[i * SH + j];
  Wfull[c * SH + j] = p;
}

// ---------------- K2: W1comb[e][h][d] bf16 (scatter + folded sinfo) ----------
__global__ __launch_bounds__(256) void k_w1c(
    const float* __restrict__ W1, const float* __restrict__ b1,
    const int* __restrict__ inv, const float* __restrict__ Wfull,
    const float* __restrict__ bfull,
    unsigned short* __restrict__ W1eT, float* __restrict__ b1c) {
  __shared__ float w1b[SH];
  __shared__ float bf[SH];
  const int e = blockIdx.x >> 7, h = blockIdx.x & 127;
  const int t = threadIdx.x;
  const float* We = W1 + (size_t)e * (SEL + SH) * HID;
  if (t < SH) { w1b[t] = We[(size_t)(SEL + t) * HID + h]; bf[t] = bfull[t]; }
  __syncthreads();
  const int* iv = inv + e * D;
  unsigned short* dst = W1eT + ((size_t)e * HID + h) * D;
  #pragma unroll
  for (int it = 0; it < 4; ++it) {
    int d = t + it * 256;
    int s = iv[d];
    float v = (s >= 0) ? We[(size_t)s * HID + h] : 0.f;
    if (d >= 512) {
      const float* wf = Wfull + (size_t)(d - 512) * SH;
      float p = 0.f;
      #pragma unroll
      for (int j = 0; j < SH; ++j) p += wf[j] * w1b[j];
      v += p;
    }
    dst[d] = f2bf(v);
  }
  if (t == 0) {
    float p = b1[e * HID + h];
    for (int j = 0; j < SH; ++j) p += bf[j] * w1b[j];
    b1c[e * HID + h] = p;
  }
}

// ---------------- K3: gate logits (fp32) + optional bf16 x conversion -------
template<bool WRITE_XBF>
__global__ __launch_bounds__(256) void k_xbf_gate(
    const float* __restrict__ x, const float* __restrict__ Wg,
    const float* __restrict__ bg, unsigned short* __restrict__ xbf,
    float* __restrict__ gl) {
  const int w = threadIdx.x >> 6, lane = threadIdx.x & 63;
  const int wid = blockIdx.x * 4 + w;
  float wg[4][4][E];
  #pragma unroll
  for (int i = 0; i < 4; ++i)
    #pragma unroll
    for (int q = 0; q < 4; ++q) {
      const float* wr = Wg + (size_t)(i * 256 + lane * 4 + q) * E;
      #pragma unroll
      for (int e2 = 0; e2 < E; ++e2) wg[i][q][e2] = wr[e2];
    }
  for (int tok = wid * 4; tok < wid * 4 + 4; ++tok) {
    const float4* xp = (const float4*)(x + (size_t)tok * D);
    float acc[E] = {};
    #pragma unroll
    for (int i = 0; i < 4; ++i) {
      float4 v = xp[i * 64 + lane];
      if (WRITE_XBF) {
        ushort4 h4;
        h4.x = f2bf(v.x); h4.y = f2bf(v.y); h4.z = f2bf(v.z); h4.w = f2bf(v.w);
        *(ushort4*)((char*)xbf + (size_t)tok * 2048 + i * 512 + lane * 8) = h4;
      }
      #pragma unroll
      for (int q = 0; q < 4; ++q) {
        float xv = (&v.x)[q];
        #pragma unroll
        for (int e2 = 0; e2 < E; ++e2) acc[e2] += xv * wg[i][q][e2];
      }
    }
    #pragma unroll
    for (int e2 = 0; e2 < E; ++e2) {
      float s = acc[e2];
      s += __shfl_xor(s, 1); s += __shfl_xor(s, 2); s += __shfl_xor(s, 4);
      s += __shfl_xor(s, 8); s += __shfl_xor(s, 16); s += __shfl_xor(s, 32);
      acc[e2] = s;
    }
    if (lane == 0) {
      #pragma unroll
      for (int e2 = 0; e2 < E; ++e2) gl[(size_t)tok * E + e2] = acc[e2] + bg[e2];
    }
  }
}

// ---------------- K4: top-3 + softmax -> per-expert compacted lists ---------
__global__ __launch_bounds__(256) void k_topk(
    const float* __restrict__ gl, int* __restrict__ cnt,
    int* __restrict__ clist, float* __restrict__ wlist) {
  const int tok = blockIdx.x * 256 + threadIdx.x;
  const int lane = threadIdx.x & 63;
  float gv[E];
  #pragma unroll
  for (int e2 = 0; e2 < E; ++e2) gv[e2] = gl[(size_t)tok * E + e2];
  int idx[K]; float sc[K];
  bool used[E] = {};
  #pragma unroll
  for (int k = 0; k < K; ++k) {
    float best = -1e30f; int bi = 0;
    for (int e2 = 0; e2 < E; ++e2)
      if (!used[e2] && gv[e2] > best) { best = gv[e2]; bi = e2; }
    used[bi] = true; sc[k] = best; idx[k] = bi;
  }
  float s1 = __expf(sc[1] - sc[0]), s2 = __expf(sc[2] - sc[0]);
  float inv_s = 1.f / (1.f + s1 + s2);
  float tw[K] = {inv_s, s1 * inv_s, s2 * inv_s};
  const unsigned long long below = (1ULL << lane) - 1ULL;
  #pragma unroll
  for (int e2 = 0; e2 < E; ++e2) {
    int myk = -1;
    #pragma unroll
    for (int k = 0; k < K; ++k) if (idx[k] == e2) myk = k;
    unsigned long long m = __ballot(myk >= 0);
    if (m) {
      int tot = __popcll(m);
      int leader = __ffsll((long long)m) - 1;
      int base = 0;
      if (lane == leader) base = atomicAdd(&cnt[e2], tot);
      base = __shfl(base, leader);
      if (myk >= 0) {
        int pos = base + __popcll(m & below);
        clist[e2 * B + pos] = (tok << 2) | myk;
        wlist[e2 * B + pos] = tw[myk];
      }
    }
  }
}

// ---------------- K5: compacted per-expert GEMM + relu·W2 epilogue ----------
template<int AMODE>
__global__ __launch_bounds__(256) void k_gemm(
    const float* __restrict__ x, const unsigned short* __restrict__ xbf,
    const unsigned short* __restrict__ W1eT,
    const int* __restrict__ cnt, const int* __restrict__ clist,
    const float* __restrict__ wlist,
    const float* __restrict__ b1c, const float* __restrict__ W2,
    const float* __restrict__ b2, float* __restrict__ eo4) {
  __shared__ __align__(16) char ldsA[128 * 128];
  __shared__ __align__(16) char ldsB[128 * 128];
  __shared__ int tokl[128];
  __shared__ float red[128];

  const int t = threadIdx.x;
  const int e = blockIdx.x >> 8;     // grid = E * 256
  const int bm = blockIdx.x & 255;
  const int n = cnt[e];
  if (bm * 128 >= n) return;
  const int cb = e * B;

  if (t < 128) {
    int gr = bm * 128 + t;
    tokl[t] = clist[cb + (gr < n ? gr : 0)] >> 2;
  }
  __syncthreads();

  const int w = t >> 6, lane = t & 63;
  const int g = lane >> 4, j = lane & 15;
  const int swz = ((lane & 7) * 16) ^ ((lane >> 3) << 4);

  const char* srcB[4];
  #pragma unroll
  for (int q = 0; q < 4; ++q)
    srcB[q] = (const char*)W1eT +
              (size_t)(e * HID + w * 32 + q * 8 + (lane >> 3)) * (D * 2) + swz;
  const char* srcA[4];
  if (AMODE == 0) {
    #pragma unroll
    for (int q = 0; q < 4; ++q)
      srcA[q] = (const char*)xbf +
                (size_t)tokl[w * 32 + q * 8 + (lane >> 3)] * 2048 + swz;
  }

  f32x4 acc[2][8] = {};

  for (int kt = 0; kt < NKT; ++kt) {
    if (kt) __syncthreads();
    if (AMODE == 0) {
      #pragma unroll
      for (int q = 0; q < 4; ++q)
        gload_lds16(srcA[q] + kt * 128, ldsA + w * 4096 + q * 1024);
    }
    #pragma unroll
    for (int q = 0; q < 4; ++q)
      gload_lds16(srcB[q] + kt * 128, ldsB + w * 4096 + q * 1024);
    if (AMODE == 1) {
      #pragma unroll
      for (int it = 0; it < 8; ++it) {
        int r = (t >> 4) + it * 16;
        const float4 v =
            *(const float4*)(x + (size_t)tokl[r] * D + kt * 64 + (t & 15) * 4);
        ushort4 h4;
        h4.x = f2bf(v.x); h4.y = f2bf(v.y); h4.z = f2bf(v.z); h4.w = f2bf(v.w);
        *(ushort4*)(ldsA + r * 128 + (((t & 15) * 8) ^ ((r & 7) << 4))) = h4;
      }
    }
    __syncthreads();
    #pragma unroll
    for (int kk = 0; kk < 2; ++kk) {
      const int kb = kk * 64 + g * 16;
      bf16x8 aF[2];
      #pragma unroll
      for (int fm = 0; fm < 2; ++fm) {
        int row = w * 32 + fm * 16 + j;
        aF[fm] = *(const bf16x8*)(ldsA + row * 128 + (kb ^ ((row & 7) << 4)));
      }
      #pragma unroll
      for (int fn = 0; fn < 8; ++fn) {
        int col = fn * 16 + j;
        bf16x8 bF = *(const bf16x8*)(ldsB + col * 128 + (kb ^ ((col & 7) << 4)));
        acc[0][fn] = __builtin_amdgcn_mfma_f32_16x16x32_bf16(aF[0], bF, acc[0][fn], 0, 0, 0);
        acc[1][fn] = __builtin_amdgcn_mfma_f32_16x16x32_bf16(aF[1], bF, acc[1][fn], 0, 0, 0);
      }
    }
  }

  float vb1[8], vw2[8];
  #pragma unroll
  for (int fn = 0; fn < 8; ++fn) {
    int col = fn * 16 + j;
    vb1[fn] = b1c[e * HID + col];
    vw2[fn] = W2[e * HID + col];
  }
  #pragma unroll
  for (int fm = 0; fm < 2; ++fm) {
    #pragma unroll
    for (int r = 0; r < 4; ++r) {
      float s = 0.f;
      #pragma unroll
      for (int fn = 0; fn < 8; ++fn)
        s += fmaxf(acc[fm][fn][r] + vb1[fn], 0.f) * vw2[fn];
      s += __shfl_xor(s, 1); s += __shfl_xor(s, 2);
      s += __shfl_xor(s, 4); s += __shfl_xor(s, 8);
      if (j == 0) red[w * 32 + fm * 16 + g * 4 + r] = s;
    }
  }
  __syncthreads();
  if (t < 128) {
    int gr = bm * 128 + t;
    if (gr < n) {
      int en = clist[cb + gr];
      eo4[(size_t)(en >> 2) * 4 + (en & 3)] = wlist[cb + gr] * (red[t] + b2[e]);
    }
  }
}

// ---------------- K6: sum the 3 weighted slots ----------------
__global__ void k_comb2(const float* __restrict__ eo4, float* __restrict__ out) {
  const int tok = blockIdx.x * 256 + threadIdx.x;
  float4 v = *(const float4*)(eo4 + (size_t)tok * 4);
  out[tok] = v.x + v.y + v.z;
}

extern "C" void kernel_launch(void* const* d_in, const int* in_sizes, int n_in,
                              void* d_out, int out_size, void* d_ws, size_t ws_size,
                              hipStream_t stream) {
  const float* x   = (const float*)d_in[0];
  const float* Wv  = (const float*)d_in[3];
  const float* Wo  = (const float*)d_in[4];
  const float* bo  = (const float*)d_in[5];
  const float* Wsp = (const float*)d_in[6];
  const float* bsp = (const float*)d_in[7];
  const float* Wg  = (const float*)d_in[8];
  const float* bg  = (const float*)d_in[9];
  const float* ml  = (const float*)d_in[10];
  const float* W1  = (const float*)d_in[11];
  const float* b1  = (const float*)d_in[12];
  const float* W2  = (const float*)d_in[13];
  const float* b2  = (const float*)d_in[14];
  float* out = (float*)d_out;

  char* ws = (char*)d_ws;
  int*   inv   = (int*)ws;                       // 24 KB
  float* WoWsp = (float*)(ws + 32768);           // 8 KB
  float* Wfull = (float*)(ws + 49152);           // 64 KB
  float* bfull = (float*)(ws + 114688);          // 128 B
  float* b1c   = (float*)(ws + 118784);          // 3 KB
  int*   cnt   = (int*)(ws + 126976);            // 32 B
  float* gl    = (float*)(ws + 131072);          // 768 KB
  int*   clist = (int*)(ws + 917504);            // 768 KB
  float* wlist = (float*)(ws + 1703936);         // 768 KB
  float* eo4   = (float*)(ws + 2490368);         // 512 KB
  unsigned short* W1eT = (unsigned short*)(ws + 3014656);  // 1.5 MB
  unsigned short* xbf  = (unsigned short*)(ws + 4587520);  // 64 MB (optional)
  const bool use_xbf = ws_size >= (size_t)4587520 + (size_t)B * D * 2;

  k_sel<<<E, D, 0, stream>>>(ml, inv, cnt);
  k_wowsp<<<65, 256, 0, stream>>>(Wo, Wsp, bo, bsp, WoWsp, bfull);
  k_wfull2<<<64, 256, 0, stream>>>(Wv, WoWsp, Wfull);
  k_w1c<<<E * HID, 256, 0, stream>>>(W1, b1, inv, Wfull, bfull, W1eT, b1c);
  if (use_xbf)
    k_xbf_gate<true><<<B / 16, 256, 0, stream>>>(x, Wg, bg, xbf, gl);
  else
    k_xbf_gate<false><<<B / 16, 256, 0, stream>>>(x, Wg, bg, xbf, gl);
  k_topk<<<B / 256, 256, 0, stream>>>(gl, cnt, clist, wlist);
  if (use_xbf)
    k_gemm<0><<<E * 256, 256, 0, stream>>>(x, xbf, W1eT, cnt, clist, wlist, b1c, W2, b2, eo4);
  else
    k_gemm<1><<<E * 256, 256, 0, stream>>>(x, xbf, W1eT, cnt, clist, wlist, b1c, W2, b2, eo4);
  k_comb2<<<B / 256, 256, 0, stream>>>(eo4, out);
}